// Round 1
// baseline (61.838 us; speedup 1.0000x reference)
//
#include <hip/hip_runtime.h>

#define DEV __device__ __forceinline__

// One wave (64 lanes) simulates one sample's 1024-amplitude state.
// Each lane holds 16 complex amplitudes in registers: flat idx = lane*16 + j.
// Wire w corresponds to bit (9-w) of the flat index:
//   wires 0..5 -> lane bits 5..0 (cross-lane via shfl_xor)
//   wires 6..9 -> local bits 3..0 (in-register)

DEV float shx(float v, int m) { return __shfl_xor(v, m, 64); }

// ---------------- single-qubit gates ----------------

// complex 2x2 gate on a LOCAL bit (mask M in 1,2,4,8)
template <int M>
DEV void gate_local_c(float (&re)[16], float (&im)[16],
                      float u00r, float u00i, float u01r, float u01i,
                      float u10r, float u10i, float u11r, float u11i) {
#pragma unroll
  for (int j = 0; j < 16; ++j) {
    if (j & M) continue;
    const int k = j | M;
    float a0r = re[j], a0i = im[j], a1r = re[k], a1i = im[k];
    re[j] = u00r * a0r - u00i * a0i + u01r * a1r - u01i * a1i;
    im[j] = u00r * a0i + u00i * a0r + u01r * a1i + u01i * a1r;
    re[k] = u10r * a0r - u10i * a0i + u11r * a1r - u11i * a1i;
    im[k] = u10r * a0i + u10i * a0r + u11r * a1i + u11i * a1r;
  }
}

// complex 2x2 gate on a LANE bit (lane mask M in 1..32)
template <int M>
DEV void gate_lane_c(float (&re)[16], float (&im)[16], int lane,
                     float u00r, float u00i, float u01r, float u01i,
                     float u10r, float u10i, float u11r, float u11i) {
  const bool hi = (lane & M) != 0;
  // coeff of a0 (bit=0 amp) and a1 (bit=1 amp) for THIS lane's output
  float c0r = hi ? u10r : u00r, c0i = hi ? u10i : u00i;
  float c1r = hi ? u11r : u01r, c1i = hi ? u11i : u01i;
#pragma unroll
  for (int j = 0; j < 16; ++j) {
    float pr = shx(re[j], M), pi = shx(im[j], M);
    float a0r = hi ? pr : re[j], a0i = hi ? pi : im[j];
    float a1r = hi ? re[j] : pr, a1i = hi ? im[j] : pi;
    re[j] = c0r * a0r - c0i * a0i + c1r * a1r - c1i * a1i;
    im[j] = c0r * a0i + c0i * a0r + c1r * a1i + c1i * a1r;
  }
}

// real RY gate [[c,-s],[s,c]] on a LOCAL bit
template <int M>
DEV void ry_local(float (&re)[16], float (&im)[16], float c, float s) {
#pragma unroll
  for (int j = 0; j < 16; ++j) {
    if (j & M) continue;
    const int k = j | M;
    float a0r = re[j], a0i = im[j], a1r = re[k], a1i = im[k];
    re[j] = c * a0r - s * a1r;
    im[j] = c * a0i - s * a1i;
    re[k] = s * a0r + c * a1r;
    im[k] = s * a0i + c * a1i;
  }
}

// real RY gate on a LANE bit
template <int M>
DEV void ry_lane(float (&re)[16], float (&im)[16], int lane, float c, float s) {
  const bool hi = (lane & M) != 0;
  float c0 = hi ? s : c;   // coeff of a0
  float c1 = hi ? c : -s;  // coeff of a1
#pragma unroll
  for (int j = 0; j < 16; ++j) {
    float pr = shx(re[j], M), pi = shx(im[j], M);
    float a0r = hi ? pr : re[j], a0i = hi ? pi : im[j];
    float a1r = hi ? re[j] : pr, a1i = hi ? im[j] : pi;
    re[j] = c0 * a0r + c1 * a1r;
    im[j] = c0 * a0i + c1 * a1i;
  }
}

// ---------------- CNOTs (control mask CM, target mask TM) ----------------

template <int CM, int TM>  // both lane bits
DEV void cnot_lane_lane(float (&re)[16], float (&im)[16], int lane) {
  const bool ctrl = (lane & CM) != 0;
#pragma unroll
  for (int j = 0; j < 16; ++j) {
    float pr = shx(re[j], TM), pi = shx(im[j], TM);
    re[j] = ctrl ? pr : re[j];
    im[j] = ctrl ? pi : im[j];
  }
}

template <int CM, int TM>  // control = lane bit, target = local bit
DEV void cnot_lane_local(float (&re)[16], float (&im)[16], int lane) {
  const bool ctrl = (lane & CM) != 0;
#pragma unroll
  for (int j = 0; j < 16; ++j) {
    if (j & TM) continue;
    const int k = j | TM;
    float tr = re[j], ti = im[j];
    re[j] = ctrl ? re[k] : re[j];
    im[j] = ctrl ? im[k] : im[j];
    re[k] = ctrl ? tr : re[k];
    im[k] = ctrl ? ti : im[k];
  }
}

template <int CM, int TM>  // both local bits: static register swap (free after SSA)
DEV void cnot_local_local(float (&re)[16], float (&im)[16]) {
#pragma unroll
  for (int j = 0; j < 16; ++j) {
    if ((j & CM) && !(j & TM)) {
      const int k = j | TM;
      float tr = re[j]; re[j] = re[k]; re[k] = tr;
      float ti = im[j]; im[j] = im[k]; im[k] = ti;
    }
  }
}

// ---------------- per-wire dispatch (w is compile-time after unroll) ----------

DEV void ry_wire(int w, float (&re)[16], float (&im)[16], int lane, float c, float s) {
  switch (w) {
    case 0: ry_lane<32>(re, im, lane, c, s); break;
    case 1: ry_lane<16>(re, im, lane, c, s); break;
    case 2: ry_lane<8>(re, im, lane, c, s); break;
    case 3: ry_lane<4>(re, im, lane, c, s); break;
    case 4: ry_lane<2>(re, im, lane, c, s); break;
    case 5: ry_lane<1>(re, im, lane, c, s); break;
    case 6: ry_local<8>(re, im, c, s); break;
    case 7: ry_local<4>(re, im, c, s); break;
    case 8: ry_local<2>(re, im, c, s); break;
    case 9: ry_local<1>(re, im, c, s); break;
  }
}

DEV void rot_wire(int w, float (&re)[16], float (&im)[16], int lane,
                  const float* __restrict__ pp) {
  // PennyLane Rot = RZ(om) @ RY(th) @ RZ(ph)
  // u00 = c*e^{-i(ph+om)/2}, u01 = -s*e^{+i(ph-om)/2}
  // u10 = s*e^{-i(ph-om)/2}, u11 = c*e^{+i(ph+om)/2}
  float ph = pp[0], th = pp[1], om = pp[2];
  float s, c;   __sincosf(0.5f * th, &s, &c);
  float sa, ca; __sincosf(0.5f * (ph + om), &sa, &ca);
  float sb, cb; __sincosf(0.5f * (ph - om), &sb, &cb);
  float u00r = c * ca, u00i = -c * sa;
  float u01r = -s * cb, u01i = -s * sb;
  float u10r = s * cb, u10i = -s * sb;
  float u11r = c * ca, u11i = c * sa;
  switch (w) {
    case 0: gate_lane_c<32>(re, im, lane, u00r, u00i, u01r, u01i, u10r, u10i, u11r, u11i); break;
    case 1: gate_lane_c<16>(re, im, lane, u00r, u00i, u01r, u01i, u10r, u10i, u11r, u11i); break;
    case 2: gate_lane_c<8>(re, im, lane, u00r, u00i, u01r, u01i, u10r, u10i, u11r, u11i); break;
    case 3: gate_lane_c<4>(re, im, lane, u00r, u00i, u01r, u01i, u10r, u10i, u11r, u11i); break;
    case 4: gate_lane_c<2>(re, im, lane, u00r, u00i, u01r, u01i, u10r, u10i, u11r, u11i); break;
    case 5: gate_lane_c<1>(re, im, lane, u00r, u00i, u01r, u01i, u10r, u10i, u11r, u11i); break;
    case 6: gate_local_c<8>(re, im, u00r, u00i, u01r, u01i, u10r, u10i, u11r, u11i); break;
    case 7: gate_local_c<4>(re, im, u00r, u00i, u01r, u01i, u10r, u10i, u11r, u11i); break;
    case 8: gate_local_c<2>(re, im, u00r, u00i, u01r, u01i, u10r, u10i, u11r, u11i); break;
    case 9: gate_local_c<1>(re, im, u00r, u00i, u01r, u01i, u10r, u10i, u11r, u11i); break;
  }
}

DEV void cnot_wire(int w, float (&re)[16], float (&im)[16], int lane) {
  switch (w) {
    case 0: cnot_lane_lane<32, 16>(re, im, lane); break;
    case 1: cnot_lane_lane<16, 8>(re, im, lane); break;
    case 2: cnot_lane_lane<8, 4>(re, im, lane); break;
    case 3: cnot_lane_lane<4, 2>(re, im, lane); break;
    case 4: cnot_lane_lane<2, 1>(re, im, lane); break;
    case 5: cnot_lane_local<1, 8>(re, im, lane); break;
    case 6: cnot_local_local<8, 4>(re, im); break;
    case 7: cnot_local_local<4, 2>(re, im); break;
    case 8: cnot_local_local<2, 1>(re, im); break;
  }
}

// ---------------- kernel ----------------

__global__ __launch_bounds__(256) void qreg_kernel(
    const float* __restrict__ x,      // (B, 10)
    const float* __restrict__ params, // (60,)
    const float* __restrict__ hw,     // (20,)
    const float* __restrict__ hb,     // (1,)
    float* __restrict__ out,          // (B,)
    int Bn) {
  const int lane = threadIdx.x & 63;
  const int b = blockIdx.x * 4 + (threadIdx.x >> 6);
  if (b >= Bn) return;

  float re[16], im[16];
#pragma unroll
  for (int j = 0; j < 16; ++j) { re[j] = 0.f; im[j] = 0.f; }
  if (lane == 0) re[0] = 1.f;

  // RY encoding (per-sample angles)
#pragma unroll
  for (int w = 0; w < 10; ++w) {
    float s, c;
    __sincosf(0.5f * x[b * 10 + w], &s, &c);
    ry_wire(w, re, im, lane, c, s);
  }

  // 2 layers of Rot + CNOT chain (shared params)
#pragma unroll
  for (int l = 0; l < 2; ++l) {
#pragma unroll
    for (int w = 0; w < 10; ++w)
      rot_wire(w, re, im, lane, params + (l * 10 + w) * 3);
#pragma unroll
    for (int w = 0; w < 9; ++w)
      cnot_wire(w, re, im, lane);
  }

  // features folded directly into head dot-product
  float p_[16];
  float S = 0.f;
#pragma unroll
  for (int j = 0; j < 16; ++j) {
    p_[j] = re[j] * re[j] + im[j] * im[j];
    S += p_[j];
  }
  float acc = 0.f;
  // <Z_w>, lane wires 0..5: sign uniform per lane
#pragma unroll
  for (int w = 0; w < 6; ++w) {
    const int m = 1 << (5 - w);
    acc += hw[w] * ((lane & m) ? -S : S);
  }
  // <Z_w>, local wires 6..9
#pragma unroll
  for (int w = 6; w < 10; ++w) {
    const int m = 1 << (9 - w);
    float t = 0.f;
#pragma unroll
    for (int j = 0; j < 16; ++j) t += (j & m) ? -p_[j] : p_[j];
    acc += hw[w] * t;
  }
  // <X_w>, lane wires 0..5: sum over all lanes counts each pair twice = 2*Re(sum)
#pragma unroll
  for (int w = 0; w < 6; ++w) {
    const int m = 1 << (5 - w);
    float t = 0.f;
#pragma unroll
    for (int j = 0; j < 16; ++j)
      t += re[j] * shx(re[j], m) + im[j] * shx(im[j], m);
    acc += hw[10 + w] * t;
  }
  // <X_w>, local wires 6..9
#pragma unroll
  for (int w = 6; w < 10; ++w) {
    const int m = 1 << (9 - w);
    float t = 0.f;
#pragma unroll
    for (int j = 0; j < 16; ++j)
      t += re[j] * re[j ^ m] + im[j] * im[j ^ m];
    acc += hw[10 + w] * t;
  }

  // single butterfly reduction over the wave
#pragma unroll
  for (int off = 32; off >= 1; off >>= 1) acc += shx(acc, off);
  if (lane == 0) out[b] = acc + hb[0];
}

extern "C" void kernel_launch(void* const* d_in, const int* in_sizes, int n_in,
                              void* d_out, int out_size, void* d_ws, size_t ws_size,
                              hipStream_t stream) {
  const float* x      = (const float*)d_in[0];
  const float* params = (const float*)d_in[1];
  const float* hw     = (const float*)d_in[2];
  const float* hb     = (const float*)d_in[3];
  float* out = (float*)d_out;
  const int B = in_sizes[0] / 10;
  const int blocks = (B + 3) / 4;  // 4 waves (samples) per 256-thread block
  qreg_kernel<<<blocks, 256, 0, stream>>>(x, params, hw, hb, out, B);
}

// Round 7
// 51.302 us; speedup vs baseline: 1.2054x; 1.2054x over previous
//
#include <hip/hip_runtime.h>

#define DEV __device__ __forceinline__

// One wave (64 lanes) simulates one sample's 1024-amplitude state.
// flat idx = lane*16 + j ; wire w <-> flat bit (9-w):
//   wires 0..5 -> lane bits 5..0 (masks 32,16,8,4,2,1)
//   wires 6..9 -> local bits 3..0 (masks 8,4,2,1 within j)
//
// Cross-lane partner exchange x[lane^M]:
//   mask 32 : __shfl_xor(v,32)           (bpermute; HW-verified in R1 kernel)
//   mask 16 : ds_swizzle 0x401F          (xor16 bit-mode; ISA-guide constant)
//   mask 8  : DPP row_ror:8   (0x128)    (ror 8 on 16-lane row == xor 8)
//   mask 4  : ds_swizzle 0x101F          (xor4 bit-mode; ISA-guide constant)
//   mask 2  : DPP quad_perm [2,3,0,1] (0x4E)
//   mask 1  : DPP quad_perm [1,0,3,2] (0xB1)

DEV float shx(float v, int m) { return __shfl_xor(v, m, 64); }

template <int CTRL>
DEV float dppx(float x) {
  int xi = __builtin_bit_cast(int, x);
  return __builtin_bit_cast(
      float, __builtin_amdgcn_update_dpp(xi, xi, CTRL, 0xF, 0xF, false));
}
template <int OFS>
DEV float swz(float x) {
  return __builtin_bit_cast(
      float, __builtin_amdgcn_ds_swizzle(__builtin_bit_cast(int, x), OFS));
}

template <int M>  // value at lane^M
DEV float partner(float x) {
  if constexpr (M == 32) return shx(x, 32);
  else if constexpr (M == 16) return swz<0x401F>(x);
  else if constexpr (M == 8) return dppx<0x128>(x);
  else if constexpr (M == 4) return swz<0x101F>(x);
  else if constexpr (M == 2) return dppx<0x4E>(x);
  else return dppx<0xB1>(x);
}

// ---------------- lane gates via partner exchange ---------------------------

template <int M>
DEV void ry_partg(float (&re)[16], float (&im)[16], int lane, float c, float s) {
  const float sgn = (lane & M) ? s : -s;  // out = c*own + sgn*partner
#pragma unroll
  for (int j = 0; j < 16; ++j) {
    float pr = partner<M>(re[j]), pi = partner<M>(im[j]);
    re[j] = c * re[j] + sgn * pr;
    im[j] = c * im[j] + sgn * pi;
  }
}

template <int M>
DEV void rot_partg(float (&re)[16], float (&im)[16], int lane,
                   float u00r, float u00i, float u01r, float u01i,
                   float u10r, float u10i, float u11r, float u11i) {
  const bool hi = (lane & M) != 0;
  // out = D_own*own + D_part*partner (selects hoisted out of the loop)
  float Dor = hi ? u11r : u00r, Doi = hi ? u11i : u00i;
  float Dpr = hi ? u10r : u01r, Dpi = hi ? u10i : u01i;
#pragma unroll
  for (int j = 0; j < 16; ++j) {
    float pr = partner<M>(re[j]), pi = partner<M>(im[j]);
    float nr = Dor * re[j] - Doi * im[j] + Dpr * pr - Dpi * pi;
    float ni = Dor * im[j] + Doi * re[j] + Dpr * pi + Dpi * pr;
    re[j] = nr; im[j] = ni;
  }
}

// ---------------- local-bit gates (in-register) -----------------------------

template <int M>
DEV void ry_local(float (&re)[16], float (&im)[16], float c, float s) {
#pragma unroll
  for (int j = 0; j < 16; ++j) {
    if (j & M) continue;
    const int k = j | M;
    float a0r = re[j], a0i = im[j], a1r = re[k], a1i = im[k];
    re[j] = c * a0r - s * a1r;
    im[j] = c * a0i - s * a1i;
    re[k] = s * a0r + c * a1r;
    im[k] = s * a0i + c * a1i;
  }
}

template <int M>
DEV void gate_local_c(float (&re)[16], float (&im)[16],
                      float u00r, float u00i, float u01r, float u01i,
                      float u10r, float u10i, float u11r, float u11i) {
#pragma unroll
  for (int j = 0; j < 16; ++j) {
    if (j & M) continue;
    const int k = j | M;
    float a0r = re[j], a0i = im[j], a1r = re[k], a1i = im[k];
    re[j] = u00r * a0r - u00i * a0i + u01r * a1r - u01i * a1i;
    im[j] = u00r * a0i + u00i * a0r + u01r * a1i + u01i * a1r;
    re[k] = u10r * a0r - u10i * a0i + u11r * a1r - u11i * a1i;
    im[k] = u10r * a0i + u10i * a0r + u11r * a1i + u11i * a1r;
  }
}

// ---------------- CNOTs ------------------------------------------------------

template <int CM, int TM>  // control lane bit CM, target lane bit TM
DEV void cnot_part(float (&re)[16], float (&im)[16], int lane) {
  const bool c = (lane & CM) != 0;
#pragma unroll
  for (int j = 0; j < 16; ++j) {
    float pr = partner<TM>(re[j]), pi = partner<TM>(im[j]);
    re[j] = c ? pr : re[j];
    im[j] = c ? pi : im[j];
  }
}

template <int CM, int TM>  // control = lane bit, target = local bit
DEV void cnot_lane_local(float (&re)[16], float (&im)[16], int lane) {
  const bool ctrl = (lane & CM) != 0;
#pragma unroll
  for (int j = 0; j < 16; ++j) {
    if (j & TM) continue;
    const int k = j | TM;
    float tr = re[j], ti = im[j];
    re[j] = ctrl ? re[k] : re[j];
    im[j] = ctrl ? im[k] : im[j];
    re[k] = ctrl ? tr : re[k];
    im[k] = ctrl ? ti : im[k];
  }
}

template <int CM, int TM>  // both local: static register swap (free after SSA)
DEV void cnot_local_local(float (&re)[16], float (&im)[16]) {
#pragma unroll
  for (int j = 0; j < 16; ++j) {
    if ((j & CM) && !(j & TM)) {
      const int k = j | TM;
      float tr = re[j]; re[j] = re[k]; re[k] = tr;
      float ti = im[j]; im[j] = im[k]; im[k] = ti;
    }
  }
}

// ---------------- dispatch ---------------------------------------------------

DEV void ry_wire(int w, float (&re)[16], float (&im)[16], int lane, float c, float s) {
  switch (w) {
    case 0: ry_partg<32>(re, im, lane, c, s); break;
    case 1: ry_partg<16>(re, im, lane, c, s); break;
    case 2: ry_partg<8>(re, im, lane, c, s); break;
    case 3: ry_partg<4>(re, im, lane, c, s); break;
    case 4: ry_partg<2>(re, im, lane, c, s); break;
    case 5: ry_partg<1>(re, im, lane, c, s); break;
    case 6: ry_local<8>(re, im, c, s); break;
    case 7: ry_local<4>(re, im, c, s); break;
    case 8: ry_local<2>(re, im, c, s); break;
    case 9: ry_local<1>(re, im, c, s); break;
  }
}

DEV void rot_wire(int w, float (&re)[16], float (&im)[16], int lane,
                  const float* __restrict__ pp) {
  // PennyLane Rot = RZ(om) @ RY(th) @ RZ(ph)
  float ph = pp[0], th = pp[1], om = pp[2];
  float s, c;   __sincosf(0.5f * th, &s, &c);
  float sa, ca; __sincosf(0.5f * (ph + om), &sa, &ca);
  float sb, cb; __sincosf(0.5f * (ph - om), &sb, &cb);
  float u00r = c * ca, u00i = -c * sa;
  float u01r = -s * cb, u01i = -s * sb;
  float u10r = s * cb, u10i = -s * sb;
  float u11r = c * ca, u11i = c * sa;
  switch (w) {
    case 0: rot_partg<32>(re, im, lane, u00r, u00i, u01r, u01i, u10r, u10i, u11r, u11i); break;
    case 1: rot_partg<16>(re, im, lane, u00r, u00i, u01r, u01i, u10r, u10i, u11r, u11i); break;
    case 2: rot_partg<8>(re, im, lane, u00r, u00i, u01r, u01i, u10r, u10i, u11r, u11i); break;
    case 3: rot_partg<4>(re, im, lane, u00r, u00i, u01r, u01i, u10r, u10i, u11r, u11i); break;
    case 4: rot_partg<2>(re, im, lane, u00r, u00i, u01r, u01i, u10r, u10i, u11r, u11i); break;
    case 5: rot_partg<1>(re, im, lane, u00r, u00i, u01r, u01i, u10r, u10i, u11r, u11i); break;
    case 6: gate_local_c<8>(re, im, u00r, u00i, u01r, u01i, u10r, u10i, u11r, u11i); break;
    case 7: gate_local_c<4>(re, im, u00r, u00i, u01r, u01i, u10r, u10i, u11r, u11i); break;
    case 8: gate_local_c<2>(re, im, u00r, u00i, u01r, u01i, u10r, u10i, u11r, u11i); break;
    case 9: gate_local_c<1>(re, im, u00r, u00i, u01r, u01i, u10r, u10i, u11r, u11i); break;
  }
}

DEV void cnot_wire(int w, float (&re)[16], float (&im)[16], int lane) {
  switch (w) {
    case 0: cnot_part<32, 16>(re, im, lane); break;
    case 1: cnot_part<16, 8>(re, im, lane); break;
    case 2: cnot_part<8, 4>(re, im, lane); break;
    case 3: cnot_part<4, 2>(re, im, lane); break;
    case 4: cnot_part<2, 1>(re, im, lane); break;
    case 5: cnot_lane_local<1, 8>(re, im, lane); break;
    case 6: cnot_local_local<8, 4>(re, im); break;
    case 7: cnot_local_local<4, 2>(re, im); break;
    case 8: cnot_local_local<2, 1>(re, im); break;
  }
}

// ---------------- X features -------------------------------------------------
// partner form double-counts each (0,1) pair across the lane-sum -> equals 2*Re

template <int M>
DEV float xfeat_part(float (&re)[16], float (&im)[16]) {
  float t = 0.f;
#pragma unroll
  for (int j = 0; j < 16; ++j)
    t += re[j] * partner<M>(re[j]) + im[j] * partner<M>(im[j]);
  return t;
}

// ---------------- kernel -----------------------------------------------------

__global__ __launch_bounds__(256) void qreg_kernel(
    const float* __restrict__ x,      // (B, 10)
    const float* __restrict__ params, // (60,)
    const float* __restrict__ hw,     // (20,)
    const float* __restrict__ hb,     // (1,)
    float* __restrict__ out,          // (B,)
    int Bn) {
  const int lane = threadIdx.x & 63;
  const int b = blockIdx.x * 4 + (threadIdx.x >> 6);
  if (b >= Bn) return;

  float re[16], im[16];
#pragma unroll
  for (int j = 0; j < 16; ++j) { re[j] = 0.f; im[j] = 0.f; }
  if (lane == 0) re[0] = 1.f;

  // RY encoding (per-sample angles)
#pragma unroll
  for (int w = 0; w < 10; ++w) {
    float s, c;
    __sincosf(0.5f * x[b * 10 + w], &s, &c);
    ry_wire(w, re, im, lane, c, s);
  }

  // 2 layers of Rot + CNOT chain (shared params)
#pragma unroll
  for (int l = 0; l < 2; ++l) {
#pragma unroll
    for (int w = 0; w < 10; ++w)
      rot_wire(w, re, im, lane, params + (l * 10 + w) * 3);
#pragma unroll
    for (int w = 0; w < 9; ++w)
      cnot_wire(w, re, im, lane);
  }

  // features folded directly into head dot-product
  float p_[16];
  float S = 0.f;
#pragma unroll
  for (int j = 0; j < 16; ++j) {
    p_[j] = re[j] * re[j] + im[j] * im[j];
    S += p_[j];
  }
  float acc = 0.f;
  // <Z_w>, lane wires 0..5: sign uniform per lane
#pragma unroll
  for (int w = 0; w < 6; ++w) {
    const int m = 1 << (5 - w);
    acc += hw[w] * ((lane & m) ? -S : S);
  }
  // <Z_w>, local wires 6..9
#pragma unroll
  for (int w = 6; w < 10; ++w) {
    const int m = 1 << (9 - w);
    float t = 0.f;
#pragma unroll
    for (int j = 0; j < 16; ++j) t += (j & m) ? -p_[j] : p_[j];
    acc += hw[w] * t;
  }
  // <X_w>, lane wires 0..5
  acc += hw[10] * xfeat_part<32>(re, im);
  acc += hw[11] * xfeat_part<16>(re, im);
  acc += hw[12] * xfeat_part<8>(re, im);
  acc += hw[13] * xfeat_part<4>(re, im);
  acc += hw[14] * xfeat_part<2>(re, im);
  acc += hw[15] * xfeat_part<1>(re, im);
  // <X_w>, local wires 6..9 (j and j^m both iterate -> implicit x2)
#pragma unroll
  for (int w = 6; w < 10; ++w) {
    const int m = 1 << (9 - w);
    float t = 0.f;
#pragma unroll
    for (int j = 0; j < 16; ++j)
      t += re[j] * re[j ^ m] + im[j] * im[j ^ m];
    acc += hw[10 + w] * t;
  }

  // butterfly reduction over the wave (same partner primitives)
  acc += partner<32>(acc);
  acc += partner<16>(acc);
  acc += partner<8>(acc);
  acc += partner<4>(acc);
  acc += partner<2>(acc);
  acc += partner<1>(acc);
  if (lane == 0) out[b] = acc + hb[0];
}

extern "C" void kernel_launch(void* const* d_in, const int* in_sizes, int n_in,
                              void* d_out, int out_size, void* d_ws, size_t ws_size,
                              hipStream_t stream) {
  const float* x      = (const float*)d_in[0];
  const float* params = (const float*)d_in[1];
  const float* hw     = (const float*)d_in[2];
  const float* hb     = (const float*)d_in[3];
  float* out = (float*)d_out;
  const int B = in_sizes[0] / 10;
  const int blocks = (B + 3) / 4;  // 4 waves (samples) per 256-thread block
  qreg_kernel<<<blocks, 256, 0, stream>>>(x, params, hw, hb, out, B);
}